// Round 1
// baseline (4920.096 us; speedup 1.0000x reference)
//
#include <hip/hip_runtime.h>
#include <math.h>

// Problem constants (from reference)
#define NN 50000      // nodes
#define NE 200000     // edges
#define INCH 768
#define HID 128
#define HEADS 4
#define NLAYERS 3
#define NNC 9
#define NEC 6

__device__ __forceinline__ float gelu_f(float v) {
    // exact (erf) GELU, matches jax.nn.gelu(approximate=False)
    return 0.5f * v * (1.0f + erff(v * 0.7071067811865475f));
}
__device__ __forceinline__ float lrelu_f(float v) {
    return v > 0.f ? v : 0.2f * v;  // PyG default negative_slope
}
// monotonic float<->uint encoding for atomicMax on floats (handles negatives)
__device__ __forceinline__ unsigned enc_f(float f) {
    unsigned u = __float_as_uint(f);
    return (u & 0x80000000u) ? ~u : (u | 0x80000000u);
}
__device__ __forceinline__ float dec_f(unsigned k) {
    unsigned u = (k & 0x80000000u) ? (k ^ 0x80000000u) : ~k;
    return __uint_as_float(u);
}

// ---------------------------------------------------------------------------
// Tiled f32 GEMM: C[M x 128] = act(A[M x K] @ W[K x 128] + bias)
// 64-row x 128-col tile per 256-thread block; BK=32.
// As stored transposed [k][m] (pad 68) so the a-fragment is a float4 read.
// ACT: 0 = none, 1 = gelu
// ---------------------------------------------------------------------------
template<int ACT>
__global__ __launch_bounds__(256) void gemm_k(
    const float* __restrict__ A, const float* __restrict__ W,
    const float* __restrict__ bias, float* __restrict__ C,
    int M, int K)
{
    __shared__ float As[32][68];
    __shared__ float Ws[32][132];
    const int t = threadIdx.x;
    const int bm = blockIdx.x * 64;
    const int tn0 = (t & 15) * 8;   // 16 groups along N
    const int tm0 = (t >> 4) * 4;   // 16 groups along M
    const int a_k4 = (t & 7) * 4;   // A loader: float4 k-offset
    const int a_r  = t >> 3;        // A loader: row within pass (0..31)
    const int w_n4 = (t & 31) * 4;  // W loader: float4 n-offset
    const int w_k  = t >> 5;        // W loader: k row (0..7)

    float acc[4][8];
#pragma unroll
    for (int i = 0; i < 4; ++i)
#pragma unroll
        for (int j = 0; j < 8; ++j) acc[i][j] = 0.f;

    for (int k0 = 0; k0 < K; k0 += 32) {
#pragma unroll
        for (int p = 0; p < 2; ++p) {
            int m = a_r + p * 32;
            int gm = bm + m;
            float4 v = make_float4(0.f, 0.f, 0.f, 0.f);
            if (gm < M) v = *(const float4*)(A + (size_t)gm * K + k0 + a_k4);
            As[a_k4 + 0][m] = v.x;
            As[a_k4 + 1][m] = v.y;
            As[a_k4 + 2][m] = v.z;
            As[a_k4 + 3][m] = v.w;
        }
#pragma unroll
        for (int p = 0; p < 4; ++p) {
            int k = w_k + p * 8;
            *(float4*)(&Ws[k][w_n4]) = *(const float4*)(W + (size_t)(k0 + k) * HID + w_n4);
        }
        __syncthreads();
#pragma unroll
        for (int kk = 0; kk < 32; ++kk) {
            float4 a4  = *(const float4*)(&As[kk][tm0]);
            float4 b4l = *(const float4*)(&Ws[kk][tn0]);
            float4 b4h = *(const float4*)(&Ws[kk][tn0 + 4]);
            float av[4] = {a4.x, a4.y, a4.z, a4.w};
            float bv[8] = {b4l.x, b4l.y, b4l.z, b4l.w, b4h.x, b4h.y, b4h.z, b4h.w};
#pragma unroll
            for (int i = 0; i < 4; ++i)
#pragma unroll
                for (int j = 0; j < 8; ++j)
                    acc[i][j] = fmaf(av[i], bv[j], acc[i][j]);
        }
        __syncthreads();
    }

    float bb[8] = {0.f,0.f,0.f,0.f,0.f,0.f,0.f,0.f};
    if (bias) {
        float4 b0 = *(const float4*)(bias + tn0);
        float4 b1 = *(const float4*)(bias + tn0 + 4);
        bb[0]=b0.x; bb[1]=b0.y; bb[2]=b0.z; bb[3]=b0.w;
        bb[4]=b1.x; bb[5]=b1.y; bb[6]=b1.z; bb[7]=b1.w;
    }
#pragma unroll
    for (int i = 0; i < 4; ++i) {
        int gm = bm + tm0 + i;
        if (gm < M) {
            float o[8];
#pragma unroll
            for (int j = 0; j < 8; ++j) {
                o[j] = acc[i][j] + bb[j];
                if (ACT == 1) o[j] = gelu_f(o[j]);
            }
            *(float4*)(C + (size_t)gm * HID + tn0)     = make_float4(o[0], o[1], o[2], o[3]);
            *(float4*)(C + (size_t)gm * HID + tn0 + 4) = make_float4(o[4], o[5], o[6], o[7]);
        }
    }
}

// ---------------------------------------------------------------------------
// Classifier head: out[M x NOUT] = gelu(A[M x K] @ W1 + b1) @ W2 + b2
// Same GEMM structure; hidden tile kept in LDS, second tiny GEMM fused.
// GATHER=true builds A rows on the fly as [h[row], h[col], ea[e]] (K=384).
// ---------------------------------------------------------------------------
template<int K, int NOUT, bool GATHER>
__global__ __launch_bounds__(256) void cls_k(
    const float* __restrict__ Ain, const float* __restrict__ hbuf,
    const float* __restrict__ eabuf, const int* __restrict__ rowi,
    const int* __restrict__ coli, const float* __restrict__ W1,
    const float* __restrict__ b1, const float* __restrict__ W2,
    const float* __restrict__ b2, float* __restrict__ out, int M)
{
    union SMem {
        struct { float As[32][68]; float Ws[32][132]; } g;
        float tt[64][129];  // hidden tile (pad 129 -> conflict-free head reads)
    };
    __shared__ SMem sm;

    const int t = threadIdx.x;
    const int bm = blockIdx.x * 64;
    const int tn0 = (t & 15) * 8;
    const int tm0 = (t >> 4) * 4;
    const int a_k4 = (t & 7) * 4;
    const int a_r  = t >> 3;
    const int w_n4 = (t & 31) * 4;
    const int w_k  = t >> 5;

    float acc[4][8];
#pragma unroll
    for (int i = 0; i < 4; ++i)
#pragma unroll
        for (int j = 0; j < 8; ++j) acc[i][j] = 0.f;

    for (int k0 = 0; k0 < K; k0 += 32) {
#pragma unroll
        for (int p = 0; p < 2; ++p) {
            int m = a_r + p * 32;
            int gm = bm + m;
            float4 v = make_float4(0.f, 0.f, 0.f, 0.f);
            if (gm < M) {
                if (GATHER) {
                    int k = k0 + a_k4;  // chunk-uniform source region (k0 mult of 32, regions mult of 128)
                    const float* bp;
                    if (k < HID)          bp = hbuf  + (size_t)rowi[gm] * HID;
                    else if (k < 2 * HID) bp = hbuf  + (size_t)coli[gm] * HID;
                    else                  bp = eabuf + (size_t)gm * HID;
                    v = *(const float4*)(bp + (k & (HID - 1)));
                } else {
                    v = *(const float4*)(Ain + (size_t)gm * K + k0 + a_k4);
                }
            }
            sm.g.As[a_k4 + 0][m] = v.x;
            sm.g.As[a_k4 + 1][m] = v.y;
            sm.g.As[a_k4 + 2][m] = v.z;
            sm.g.As[a_k4 + 3][m] = v.w;
        }
#pragma unroll
        for (int p = 0; p < 4; ++p) {
            int k = w_k + p * 8;
            *(float4*)(&sm.g.Ws[k][w_n4]) = *(const float4*)(W1 + (size_t)(k0 + k) * HID + w_n4);
        }
        __syncthreads();
#pragma unroll
        for (int kk = 0; kk < 32; ++kk) {
            float4 a4  = *(const float4*)(&sm.g.As[kk][tm0]);
            float4 b4l = *(const float4*)(&sm.g.Ws[kk][tn0]);
            float4 b4h = *(const float4*)(&sm.g.Ws[kk][tn0 + 4]);
            float av[4] = {a4.x, a4.y, a4.z, a4.w};
            float bv[8] = {b4l.x, b4l.y, b4l.z, b4l.w, b4h.x, b4h.y, b4h.z, b4h.w};
#pragma unroll
            for (int i = 0; i < 4; ++i)
#pragma unroll
                for (int j = 0; j < 8; ++j)
                    acc[i][j] = fmaf(av[i], bv[j], acc[i][j]);
        }
        __syncthreads();  // after last iter: all As/Ws reads done -> tt reuse safe
    }

    {
        float4 b0 = *(const float4*)(b1 + tn0);
        float4 b1v = *(const float4*)(b1 + tn0 + 4);
        float bb[8] = {b0.x,b0.y,b0.z,b0.w,b1v.x,b1v.y,b1v.z,b1v.w};
#pragma unroll
        for (int i = 0; i < 4; ++i)
#pragma unroll
            for (int j = 0; j < 8; ++j)
                sm.tt[tm0 + i][tn0 + j] = gelu_f(acc[i][j] + bb[j]);
    }
    __syncthreads();

    for (int o = t; o < 64 * NOUT; o += 256) {
        int r = o / NOUT;
        int j = o - r * NOUT;
        int gm = bm + r;
        if (gm < M) {
            float s = b2[j];
#pragma unroll 8
            for (int k = 0; k < HID; ++k)
                s = fmaf(sm.tt[r][k], W2[k * NOUT + j], s);
            out[(size_t)gm * NOUT + j] = s;
        }
    }
}

// ---------------------------------------------------------------------------
// Self-loop attr: la[n] = sum of ea over incoming edges; cnt[n] = in-degree.
// 32 lanes per edge, float4 per lane. (edge_index & ea are layer-invariant ->
// run once, reused by all 3 layers.)
// ---------------------------------------------------------------------------
__global__ __launch_bounds__(256) void loop_accum(const int* __restrict__ dst,
    const float* __restrict__ ea, float* __restrict__ la, float* __restrict__ cnt)
{
    int g = blockIdx.x * 8 + (threadIdx.x >> 5);
    int lane = threadIdx.x & 31;
    if (g >= NE) return;
    int d = dst[g];
    int c0 = lane * 4;
    float4 v = *(const float4*)(ea + (size_t)g * HID + c0);
    atomicAdd(&la[(size_t)d * HID + c0 + 0], v.x);
    atomicAdd(&la[(size_t)d * HID + c0 + 1], v.y);
    atomicAdd(&la[(size_t)d * HID + c0 + 2], v.z);
    atomicAdd(&la[(size_t)d * HID + c0 + 3], v.w);
    if (lane == 0) atomicAdd(&cnt[d], 1.f);
}

__global__ void loop_norm(float* __restrict__ la, const float* __restrict__ cnt)
{
    int i = blockIdx.x * 256 + threadIdx.x;
    if (i < NN * HID) la[i] = la[i] / fmaxf(cnt[i >> 7], 1.f);
}

// ---------------------------------------------------------------------------
// Attention pass 1: logits[g][h] = sum_c lrelu(xl[src]+xr[dst]+ee)[h][c]*att[h][c]
// + segment max via encoded atomicMax. g in [0, E+N): >=E are self-loops.
// ---------------------------------------------------------------------------
__global__ __launch_bounds__(256) void att_logits(const int* __restrict__ src,
    const int* __restrict__ dst, const float* __restrict__ xl,
    const float* __restrict__ xr, const float* __restrict__ eeE,
    const float* __restrict__ eeL, const float* __restrict__ attw,
    float* __restrict__ logits, unsigned* __restrict__ segmax)
{
    int g = blockIdx.x * 8 + (threadIdx.x >> 5);
    int lane = threadIdx.x & 31;
    if (g >= NE + NN) return;
    int s, d;
    const float* ee;
    if (g < NE) { s = src[g]; d = dst[g]; ee = eeE + (size_t)g * HID; }
    else        { s = g - NE; d = s;      ee = eeL + (size_t)s * HID; }
    int c0 = lane * 4;  // 8 lanes per head (32 channels)
    float4 a = *(const float4*)(xl + (size_t)s * HID + c0);
    float4 b = *(const float4*)(xr + (size_t)d * HID + c0);
    float4 e = *(const float4*)(ee + c0);
    float4 w = *(const float4*)(attw + c0);
    float sum = lrelu_f(a.x + b.x + e.x) * w.x
              + lrelu_f(a.y + b.y + e.y) * w.y
              + lrelu_f(a.z + b.z + e.z) * w.z
              + lrelu_f(a.w + b.w + e.w) * w.w;
    sum += __shfl_xor(sum, 1);
    sum += __shfl_xor(sum, 2);
    sum += __shfl_xor(sum, 4);
    if ((lane & 7) == 0) {
        int hh = lane >> 3;
        logits[(size_t)g * HEADS + hh] = sum;
        atomicMax(&segmax[d * HEADS + hh], enc_f(sum));
    }
}

// Attention pass 2: e = exp(logit - segmax); segsum += e (alpha stored in-place)
__global__ void att_expsum(const int* __restrict__ dst, float* __restrict__ logits,
    const unsigned* __restrict__ segmax, float* __restrict__ segsum)
{
    int i = blockIdx.x * 256 + threadIdx.x;
    if (i >= (NE + NN) * HEADS) return;
    int g = i >> 2;
    int hh = i & 3;
    int d = (g < NE) ? dst[g] : g - NE;
    float m = dec_f(segmax[d * HEADS + hh]);
    float ev = expf(logits[i] - m);
    logits[i] = ev;
    atomicAdd(&segsum[d * HEADS + hh], ev);
}

// Attention pass 3: out[dst] += xl[src] * alpha/(segsum+eps)
__global__ __launch_bounds__(256) void att_scatter(const int* __restrict__ src,
    const int* __restrict__ dst, const float* __restrict__ xl,
    const float* __restrict__ alpha, const float* __restrict__ segsum,
    float* __restrict__ outb)
{
    int g = blockIdx.x * 8 + (threadIdx.x >> 5);
    int lane = threadIdx.x & 31;
    if (g >= NE + NN) return;
    int s, d;
    if (g < NE) { s = src[g]; d = dst[g]; } else { s = g - NE; d = s; }
    int hh = lane >> 3;
    float a = alpha[(size_t)g * HEADS + hh] / (segsum[d * HEADS + hh] + 1e-16f);
    int c0 = lane * 4;
    float4 v = *(const float4*)(xl + (size_t)s * HID + c0);
    atomicAdd(&outb[(size_t)d * HID + c0 + 0], v.x * a);
    atomicAdd(&outb[(size_t)d * HID + c0 + 1], v.y * a);
    atomicAdd(&outb[(size_t)d * HID + c0 + 2], v.z * a);
    atomicAdd(&outb[(size_t)d * HID + c0 + 3], v.w * a);
}

// h = gelu(outb + conv_bias) + h (residual)
__global__ void layer_epi(float* __restrict__ h, const float* __restrict__ outb,
    const float* __restrict__ bias)
{
    int i = blockIdx.x * 256 + threadIdx.x;
    if (i < NN * HID) {
        float v = outb[i] + bias[i & 127];
        h[i] = gelu_f(v) + h[i];
    }
}

// ---------------------------------------------------------------------------
extern "C" void kernel_launch(void* const* d_in, const int* in_sizes, int n_in,
                              void* d_out, int out_size, void* d_ws, size_t ws_size,
                              hipStream_t stream)
{
    const float* x          = (const float*)d_in[0];
    const float* edge_attr  = (const float*)d_in[1];
    const int*   edge_index = (const int*)  d_in[2];
    const float* node_w     = (const float*)d_in[3];
    const float* node_b     = (const float*)d_in[4];
    const float* edge_w     = (const float*)d_in[5];
    const float* edge_b     = (const float*)d_in[6];
    const float* lin_l_w    = (const float*)d_in[7];
    const float* lin_l_b    = (const float*)d_in[8];
    const float* lin_r_w    = (const float*)d_in[9];
    const float* lin_r_b    = (const float*)d_in[10];
    const float* lin_edge_w = (const float*)d_in[11];
    const float* att        = (const float*)d_in[12];
    const float* conv_bias  = (const float*)d_in[13];
    const float* nc_w1      = (const float*)d_in[14];
    const float* nc_b1      = (const float*)d_in[15];
    const float* nc_w2      = (const float*)d_in[16];
    const float* nc_b2      = (const float*)d_in[17];
    const float* ec_w1      = (const float*)d_in[18];
    const float* ec_b1      = (const float*)d_in[19];
    const float* ec_w2      = (const float*)d_in[20];
    const float* ec_b2      = (const float*)d_in[21];

    const int* src = edge_index;       // edge_index[0]
    const int* dst = edge_index + NE;  // edge_index[1]

    // workspace carve-up (~365 MB total, f32)
    float* ws = (float*)d_ws;
    size_t off = 0;
    auto take = [&](size_t n) { float* p = ws + off; off += (n + 63) & ~(size_t)63; return p; };
    float* h      = take((size_t)NN * HID);
    float* ea     = take((size_t)NE * HID);
    float* xl     = take((size_t)NN * HID);
    float* xr     = take((size_t)NN * HID);
    float* eeE    = take((size_t)NE * HID);
    float* eeL    = take((size_t)NN * HID);
    float* la     = take((size_t)NN * HID);
    float* outb   = take((size_t)NN * HID);
    float* logits = take((size_t)(NE + NN) * HEADS);  // reused as alpha in-place
    float* segsum = take((size_t)NN * HEADS);
    float* cnt    = take((size_t)NN);
    unsigned* segmax = (unsigned*)take((size_t)NN * HEADS);

    dim3 B(256);
    const int gN  = (NN + 63) / 64;        // 782 row-tiles over nodes
    const int gE  = (NE + 63) / 64;        // 3125 row-tiles over edges
    const int gEN = (NE + NN) / 8;         // 31250 (exact)

    // input projections (+erf-GELU)
    gemm_k<1><<<gN, B, 0, stream>>>(x, node_w, node_b, h, NN, INCH);
    gemm_k<1><<<gE, B, 0, stream>>>(edge_attr, edge_w, edge_b, ea, NE, INCH);

    // self-loop attr mean (once; ea & edge_index are layer-invariant)
    hipMemsetAsync(la,  0, (size_t)NN * HID * sizeof(float), stream);
    hipMemsetAsync(cnt, 0, (size_t)NN * sizeof(float), stream);
    loop_accum<<<NE / 8, B, 0, stream>>>(dst, ea, la, cnt);
    loop_norm<<<(NN * HID + 255) / 256, B, 0, stream>>>(la, cnt);

    for (int l = 0; l < NLAYERS; ++l) {
        const float* wl = lin_l_w    + (size_t)l * HID * HID;
        const float* wr = lin_r_w    + (size_t)l * HID * HID;
        const float* we = lin_edge_w + (size_t)l * HID * HID;
        gemm_k<0><<<gN, B, 0, stream>>>(h,  wl, lin_l_b + (size_t)l * HID, xl, NN, HID);
        gemm_k<0><<<gN, B, 0, stream>>>(h,  wr, lin_r_b + (size_t)l * HID, xr, NN, HID);
        gemm_k<0><<<gE, B, 0, stream>>>(ea, we, nullptr, eeE, NE, HID);
        gemm_k<0><<<gN, B, 0, stream>>>(la, we, nullptr, eeL, NN, HID);

        hipMemsetAsync(segmax, 0, (size_t)NN * HEADS * sizeof(unsigned), stream); // enc(0)=min
        hipMemsetAsync(segsum, 0, (size_t)NN * HEADS * sizeof(float), stream);
        hipMemsetAsync(outb,   0, (size_t)NN * HID * sizeof(float), stream);

        att_logits <<<gEN, B, 0, stream>>>(src, dst, xl, xr, eeE, eeL,
                                           att + (size_t)l * HEADS * 32, logits, segmax);
        att_expsum <<<((NE + NN) * HEADS + 255) / 256, B, 0, stream>>>(dst, logits, segmax, segsum);
        att_scatter<<<gEN, B, 0, stream>>>(src, dst, xl, logits, segsum, outb);
        layer_epi  <<<(NN * HID + 255) / 256, B, 0, stream>>>(h, outb, conv_bias + (size_t)l * HID);
    }

    // classifier heads (GEMM1+GELU+GEMM2 fused via LDS hidden tile)
    float* node_out = (float*)d_out;                    // [NN x 9]
    float* edge_out = (float*)d_out + (size_t)NN * NNC; // [NE x 6]
    cls_k<HID, NNC, false><<<gN, B, 0, stream>>>(h, nullptr, nullptr, nullptr, nullptr,
        nc_w1, nc_b1, nc_w2, nc_b2, node_out, NN);
    cls_k<3 * HID, NEC, true><<<gE, B, 0, stream>>>(nullptr, h, ea, src, dst,
        ec_w1, ec_b1, ec_w2, ec_b2, edge_out, NE);
}

// Round 6
// 3632.439 us; speedup vs baseline: 1.3545x; 1.3545x over previous
//
#include <hip/hip_runtime.h>
#include <math.h>

// Problem constants (from reference)
#define NN 50000      // nodes
#define NE 200000     // edges
#define INCH 768
#define HID 128
#define HEADS 4
#define NLAYERS 3
#define NNC 9
#define NEC 6

typedef __attribute__((ext_vector_type(8))) short bf16x8;
typedef __attribute__((ext_vector_type(4))) float f32x4;

__device__ __forceinline__ float gelu_f(float v) {
    return 0.5f * v * (1.0f + erff(v * 0.7071067811865475f));  // exact erf GELU
}
__device__ __forceinline__ float lrelu_f(float v) {
    return v > 0.f ? v : 0.2f * v;
}
__device__ __forceinline__ unsigned enc_f(float f) {
    unsigned u = __float_as_uint(f);
    return (u & 0x80000000u) ? ~u : (u | 0x80000000u);
}
__device__ __forceinline__ float dec_f(unsigned k) {
    unsigned u = (k & 0x80000000u) ? (k ^ 0x80000000u) : ~k;
    return __uint_as_float(u);
}
// f32 -> bf16 round-to-nearest-even (bit arithmetic; data has no NaN/Inf)
__device__ __forceinline__ unsigned short f2bf_rne(float f) {
    unsigned u = __float_as_uint(f);
    unsigned r = u + 0x7FFFu + ((u >> 16) & 1u);
    return (unsigned short)(r >> 16);
}
__device__ __forceinline__ float bf2f(unsigned short s) {
    return __uint_as_float(((unsigned)s) << 16);
}

// ---------------------------------------------------------------------------
// Weight prep: W[K x 128] f32 row-major -> WtHi/WtLo [128 x K] bf16 (transposed,
// error-split: w ~= hi + lo). Run once per launch; ~410k elements total.
// ---------------------------------------------------------------------------
struct WEnt { const float* src; unsigned short* hi; unsigned short* lo; int K; int nelem; };
struct WPack { WEnt e[15]; };

__global__ __launch_bounds__(256) void wprep(WPack p) {
    int g = blockIdx.x * 256 + threadIdx.x;
#pragma unroll 1
    for (int i = 0; i < 15; ++i) {
        int n = p.e[i].nelem;
        if (g < n) {
            int K = p.e[i].K;
            int k = g >> 7;          // row in src (K x 128)
            int c = g & 127;         // col in src
            float w = p.e[i].src[g];
            unsigned short h = f2bf_rne(w);
            unsigned short l = f2bf_rne(w - bf2f(h));
            p.e[i].hi[(size_t)c * K + k] = h;
            p.e[i].lo[(size_t)c * K + k] = l;
            return;
        }
        g -= n;
    }
}

// ---------------------------------------------------------------------------
// MFMA bf16x3 GEMM: C[M x 128] = act(A[M x K] @ W[K x 128] + bias)
// A f32 (converted to hi/lo bf16 in-register); W pre-split transposed bf16.
// 128x128 tile, 4 waves (2x2), 16x16x32 MFMA, acc[4][4] f32x4 per wave.
// 3 MFMAs per fragment pair: Ahi*Bhi + Alo*Bhi + Ahi*Blo (drop lo*lo).
// ---------------------------------------------------------------------------
template<int ACT>
__global__ __launch_bounds__(256, 2) void mgemm(
    const float* __restrict__ A, const unsigned short* __restrict__ WtHi,
    const unsigned short* __restrict__ WtLo, const float* __restrict__ bias,
    float* __restrict__ C, int M, int K)
{
    __shared__ float As[128][36];            // 18.0 KB, f32 [row][k]
    __shared__ unsigned short WsH[128][40];  // 10.0 KB, bf16 [col][k]
    __shared__ unsigned short WsL[128][40];  // 10.0 KB
    const int t = threadIdx.x;
    const int lane = t & 63;
    const int wid = t >> 6;
    const int wm = (wid >> 1) * 64;   // wave row base
    const int wn = (wid & 1) * 64;    // wave col base
    const int fr = lane & 15;         // fragment row/col index
    const int kg = lane >> 4;         // k-group 0..3
    const int bm = blockIdx.x * 128;

    const int a_k4 = (t & 7) * 4;
    const int a_r0 = t >> 3;
    const int w_sg = (t & 3) * 8;
    const int w_c0 = t >> 2;

    f32x4 acc[4][4] = {};

    for (int k0 = 0; k0 < K; k0 += 32) {
        // stage A tile 128x32 f32
#pragma unroll
        for (int p = 0; p < 4; ++p) {
            int row = a_r0 + p * 32;
            int gm = bm + row;
            float4 v = make_float4(0.f, 0.f, 0.f, 0.f);
            if (gm < M) v = *(const float4*)(A + (size_t)gm * K + k0 + a_k4);
            *(float4*)(&As[row][a_k4]) = v;
        }
        // stage W tiles 128x32 bf16 hi/lo
#pragma unroll
        for (int p = 0; p < 2; ++p) {
            int col = w_c0 + p * 64;
            *(uint4*)(&WsH[col][w_sg]) = *(const uint4*)(WtHi + (size_t)col * K + k0 + w_sg);
            *(uint4*)(&WsL[col][w_sg]) = *(const uint4*)(WtLo + (size_t)col * K + k0 + w_sg);
        }
        __syncthreads();

        bf16x8 bh[4], bl[4];
#pragma unroll
        for (int n = 0; n < 4; ++n) {
            int col = wn + n * 16 + fr;
            bh[n] = *(const bf16x8*)(&WsH[col][kg * 8]);
            bl[n] = *(const bf16x8*)(&WsL[col][kg * 8]);
        }
#pragma unroll
        for (int m = 0; m < 4; ++m) {
            int row = wm + m * 16 + fr;
            float av[8];
            *(float4*)(av)     = *(const float4*)(&As[row][kg * 8]);
            *(float4*)(av + 4) = *(const float4*)(&As[row][kg * 8 + 4]);
            bf16x8 ah, al;
#pragma unroll
            for (int j = 0; j < 8; ++j) {
                unsigned short hh = f2bf_rne(av[j]);
                ah[j] = (short)hh;
                al[j] = (short)f2bf_rne(av[j] - bf2f(hh));
            }
#pragma unroll
            for (int n = 0; n < 4; ++n) {
                acc[m][n] = __builtin_amdgcn_mfma_f32_16x16x32_bf16(ah, bh[n], acc[m][n], 0, 0, 0);
                acc[m][n] = __builtin_amdgcn_mfma_f32_16x16x32_bf16(al, bh[n], acc[m][n], 0, 0, 0);
                acc[m][n] = __builtin_amdgcn_mfma_f32_16x16x32_bf16(ah, bl[n], acc[m][n], 0, 0, 0);
            }
        }
        __syncthreads();
    }

    // epilogue: lane holds D[kg*4 + r][fr] of fragment (m,n)  [verified C/D map]
    float bb[4] = {0.f, 0.f, 0.f, 0.f};
    if (bias) {
#pragma unroll
        for (int n = 0; n < 4; ++n) bb[n] = bias[wn + n * 16 + fr];
    }
#pragma unroll
    for (int m = 0; m < 4; ++m) {
        int grow0 = bm + wm + m * 16 + kg * 4;
#pragma unroll
        for (int r = 0; r < 4; ++r) {
            int grow = grow0 + r;
            if (grow < M) {
                float* cp = C + (size_t)grow * HID + wn + fr;
#pragma unroll
                for (int n = 0; n < 4; ++n) {
                    float v = acc[m][n][r] + bb[n];
                    if (ACT == 1) v = gelu_f(v);
                    cp[n * 16] = v;
                }
            }
        }
    }
}

// ---------------------------------------------------------------------------
// Self-loop attr accumulation
// ---------------------------------------------------------------------------
__global__ __launch_bounds__(256) void loop_accum(const int* __restrict__ dst,
    const float* __restrict__ ea, float* __restrict__ la, float* __restrict__ cnt)
{
    int g = blockIdx.x * 8 + (threadIdx.x >> 5);
    int lane = threadIdx.x & 31;
    if (g >= NE) return;
    int d = dst[g];
    int c0 = lane * 4;
    float4 v = *(const float4*)(ea + (size_t)g * HID + c0);
    atomicAdd(&la[(size_t)d * HID + c0 + 0], v.x);
    atomicAdd(&la[(size_t)d * HID + c0 + 1], v.y);
    atomicAdd(&la[(size_t)d * HID + c0 + 2], v.z);
    atomicAdd(&la[(size_t)d * HID + c0 + 3], v.w);
    if (lane == 0) atomicAdd(&cnt[d], 1.f);
}

__global__ void loop_norm(float* __restrict__ la, const float* __restrict__ cnt)
{
    int i = blockIdx.x * 256 + threadIdx.x;
    if (i < NN * HID) la[i] = la[i] / fmaxf(cnt[i >> 7], 1.f);
}

// ---------------------------------------------------------------------------
// Attention passes
// ---------------------------------------------------------------------------
__global__ __launch_bounds__(256) void att_logits(const int* __restrict__ src,
    const int* __restrict__ dst, const float* __restrict__ xl,
    const float* __restrict__ xr, const float* __restrict__ eeE,
    const float* __restrict__ eeL, const float* __restrict__ attw,
    float* __restrict__ logits, unsigned* __restrict__ segmax)
{
    int g = blockIdx.x * 8 + (threadIdx.x >> 5);
    int lane = threadIdx.x & 31;
    if (g >= NE + NN) return;
    int s, d;
    const float* ee;
    if (g < NE) { s = src[g]; d = dst[g]; ee = eeE + (size_t)g * HID; }
    else        { s = g - NE; d = s;      ee = eeL + (size_t)s * HID; }
    int c0 = lane * 4;
    float4 a = *(const float4*)(xl + (size_t)s * HID + c0);
    float4 b = *(const float4*)(xr + (size_t)d * HID + c0);
    float4 e = *(const float4*)(ee + c0);
    float4 w = *(const float4*)(attw + c0);
    float sum = lrelu_f(a.x + b.x + e.x) * w.x
              + lrelu_f(a.y + b.y + e.y) * w.y
              + lrelu_f(a.z + b.z + e.z) * w.z
              + lrelu_f(a.w + b.w + e.w) * w.w;
    sum += __shfl_xor(sum, 1);
    sum += __shfl_xor(sum, 2);
    sum += __shfl_xor(sum, 4);
    if ((lane & 7) == 0) {
        int hh = lane >> 3;
        logits[(size_t)g * HEADS + hh] = sum;
        atomicMax(&segmax[d * HEADS + hh], enc_f(sum));
    }
}

__global__ void att_expsum(const int* __restrict__ dst, float* __restrict__ logits,
    const unsigned* __restrict__ segmax, float* __restrict__ segsum)
{
    int i = blockIdx.x * 256 + threadIdx.x;
    if (i >= (NE + NN) * HEADS) return;
    int g = i >> 2;
    int hh = i & 3;
    int d = (g < NE) ? dst[g] : g - NE;
    float m = dec_f(segmax[d * HEADS + hh]);
    float ev = expf(logits[i] - m);
    logits[i] = ev;
    atomicAdd(&segsum[d * HEADS + hh], ev);
}

__global__ __launch_bounds__(256) void att_scatter(const int* __restrict__ src,
    const int* __restrict__ dst, const float* __restrict__ xl,
    const float* __restrict__ alpha, const float* __restrict__ segsum,
    float* __restrict__ outb)
{
    int g = blockIdx.x * 8 + (threadIdx.x >> 5);
    int lane = threadIdx.x & 31;
    if (g >= NE + NN) return;
    int s, d;
    if (g < NE) { s = src[g]; d = dst[g]; } else { s = g - NE; d = s; }
    int hh = lane >> 3;
    float a = alpha[(size_t)g * HEADS + hh] / (segsum[d * HEADS + hh] + 1e-16f);
    int c0 = lane * 4;
    float4 v = *(const float4*)(xl + (size_t)s * HID + c0);
    atomicAdd(&outb[(size_t)d * HID + c0 + 0], v.x * a);
    atomicAdd(&outb[(size_t)d * HID + c0 + 1], v.y * a);
    atomicAdd(&outb[(size_t)d * HID + c0 + 2], v.z * a);
    atomicAdd(&outb[(size_t)d * HID + c0 + 3], v.w * a);
}

__global__ void layer_epi(float* __restrict__ h, const float* __restrict__ outb,
    const float* __restrict__ bias)
{
    int i = blockIdx.x * 256 + threadIdx.x;
    if (i < NN * HID) {
        float v = outb[i] + bias[i & 127];
        h[i] = gelu_f(v) + h[i];
    }
}

// ---------------------------------------------------------------------------
// Node head: out[n][j] = hid[n] @ nc_w2[:,j] + b2[j]   (hid already gelu'd)
// ---------------------------------------------------------------------------
__global__ __launch_bounds__(256) void node_head(const float* __restrict__ hid,
    const float* __restrict__ W2, const float* __restrict__ b2, float* __restrict__ out)
{
    int nidx = blockIdx.x * 4 + (threadIdx.x >> 6);
    int lane = threadIdx.x & 63;
    if (nidx >= NN) return;
    int ch = lane * 2;
    float2 v = *(const float2*)(hid + (size_t)nidx * HID + ch);
    float a[NNC];
#pragma unroll
    for (int j = 0; j < NNC; ++j)
        a[j] = v.x * W2[ch * NNC + j] + v.y * W2[(ch + 1) * NNC + j];
#pragma unroll
    for (int s = 32; s; s >>= 1)
#pragma unroll
        for (int j = 0; j < NNC; ++j) a[j] += __shfl_down(a[j], s);
    if (lane == 0) {
#pragma unroll
        for (int j = 0; j < NNC; ++j) out[(size_t)nidx * NNC + j] = a[j] + b2[j];
    }
}

// ---------------------------------------------------------------------------
// Edge head: hidden = gelu(Pa[src] + Pb[dst] + Pc[e] + b1); out = hidden@W2+b2
// ---------------------------------------------------------------------------
__global__ __launch_bounds__(256) void edge_head(
    const int* __restrict__ srci, const int* __restrict__ dsti,
    const float* __restrict__ Pa, const float* __restrict__ Pb,
    const float* __restrict__ Pc, const float* __restrict__ b1,
    const float* __restrict__ W2, const float* __restrict__ b2,
    float* __restrict__ out)
{
    int e = blockIdx.x * 4 + (threadIdx.x >> 6);
    int lane = threadIdx.x & 63;
    if (e >= NE) return;
    int r = srci[e], c = dsti[e];
    int ch = lane * 2;
    float2 pa = *(const float2*)(Pa + (size_t)r * HID + ch);
    float2 pb = *(const float2*)(Pb + (size_t)c * HID + ch);
    float2 pc = *(const float2*)(Pc + (size_t)e * HID + ch);
    float2 bb = *(const float2*)(b1 + ch);
    float h0 = gelu_f(pa.x + pb.x + pc.x + bb.x);
    float h1 = gelu_f(pa.y + pb.y + pc.y + bb.y);
    float a[NEC];
#pragma unroll
    for (int j = 0; j < NEC; ++j)
        a[j] = h0 * W2[ch * NEC + j] + h1 * W2[(ch + 1) * NEC + j];
#pragma unroll
    for (int s = 32; s; s >>= 1)
#pragma unroll
        for (int j = 0; j < NEC; ++j) a[j] += __shfl_down(a[j], s);
    if (lane == 0) {
#pragma unroll
        for (int j = 0; j < NEC; ++j) out[(size_t)e * NEC + j] = a[j] + b2[j];
    }
}

// ---------------------------------------------------------------------------
extern "C" void kernel_launch(void* const* d_in, const int* in_sizes, int n_in,
                              void* d_out, int out_size, void* d_ws, size_t ws_size,
                              hipStream_t stream)
{
    const float* x          = (const float*)d_in[0];
    const float* edge_attr  = (const float*)d_in[1];
    const int*   edge_index = (const int*)  d_in[2];
    const float* node_w     = (const float*)d_in[3];
    const float* node_b     = (const float*)d_in[4];
    const float* edge_w     = (const float*)d_in[5];
    const float* edge_b     = (const float*)d_in[6];
    const float* lin_l_w    = (const float*)d_in[7];
    const float* lin_l_b    = (const float*)d_in[8];
    const float* lin_r_w    = (const float*)d_in[9];
    const float* lin_r_b    = (const float*)d_in[10];
    const float* lin_edge_w = (const float*)d_in[11];
    const float* att        = (const float*)d_in[12];
    const float* conv_bias  = (const float*)d_in[13];
    const float* nc_w1      = (const float*)d_in[14];
    const float* nc_b1      = (const float*)d_in[15];
    const float* nc_w2      = (const float*)d_in[16];
    const float* nc_b2      = (const float*)d_in[17];
    const float* ec_w1      = (const float*)d_in[18];
    const float* ec_b1      = (const float*)d_in[19];
    const float* ec_w2      = (const float*)d_in[20];
    const float* ec_b2      = (const float*)d_in[21];

    const int* src = edge_index;
    const int* dst = edge_index + NE;

    // f32 workspace carve-up (~341 MB)
    float* ws = (float*)d_ws;
    size_t off = 0;
    auto take = [&](size_t n) { float* p = ws + off; off += (n + 63) & ~(size_t)63; return p; };
    float* h      = take((size_t)NN * HID);
    float* ea     = take((size_t)NE * HID);
    float* xl     = take((size_t)NN * HID);
    float* xr     = take((size_t)NN * HID);
    float* eeE    = take((size_t)NE * HID);
    float* eeL    = take((size_t)NN * HID);
    float* la     = take((size_t)NN * HID);
    float* outb   = take((size_t)NN * HID);
    float* logits = take((size_t)(NE + NN) * HEADS);
    float* segsum = take((size_t)NN * HEADS);
    float* cnt    = take((size_t)NN);
    unsigned* segmax = (unsigned*)take((size_t)NN * HEADS);

    // bf16 split-weight arena (+1.6 MB)
    unsigned short* warena = (unsigned short*)(ws + off);
    size_t woff = 0;
    auto wtake = [&](size_t n) { unsigned short* p = warena + woff; woff += n; return p; };

    WPack wp;
    int wi = 0;
    auto wadd = [&](const float* s, int K) {
        unsigned short* hi = wtake((size_t)HID * K);
        unsigned short* lo = wtake((size_t)HID * K);
        wp.e[wi] = { s, hi, lo, K, K * HID };
        ++wi;
        return wi - 1;
    };
    int iNode = wadd(node_w, INCH);
    int iEdge = wadd(edge_w, INCH);
    int iL[NLAYERS], iR[NLAYERS], iE[NLAYERS];
    for (int l = 0; l < NLAYERS; ++l) iL[l] = wadd(lin_l_w + (size_t)l * HID * HID, HID);
    for (int l = 0; l < NLAYERS; ++l) iR[l] = wadd(lin_r_w + (size_t)l * HID * HID, HID);
    for (int l = 0; l < NLAYERS; ++l) iE[l] = wadd(lin_edge_w + (size_t)l * HID * HID, HID);
    int iNC = wadd(nc_w1, HID);
    int iEA = wadd(ec_w1, HID);                    // rows   0..127 -> * h[src]
    int iEB = wadd(ec_w1 + (size_t)HID * HID, HID);// rows 128..255 -> * h[dst]
    int iEC = wadd(ec_w1 + (size_t)2 * HID * HID, HID); // rows 256..383 -> * ea

    dim3 B(256);
    const int gN128 = (NN + 127) / 128;   // 391
    const int gE128 = (NE + 127) / 128;   // 1563
    const int gEN   = (NE + NN) / 8;

    wprep<<<1600, B, 0, stream>>>(wp);

    // input projections (+erf GELU)
    mgemm<1><<<gN128, B, 0, stream>>>(x, wp.e[iNode].hi, wp.e[iNode].lo, node_b, h, NN, INCH);
    mgemm<1><<<gE128, B, 0, stream>>>(edge_attr, wp.e[iEdge].hi, wp.e[iEdge].lo, edge_b, ea, NE, INCH);

    // self-loop attr mean (once; layer-invariant)
    hipMemsetAsync(la,  0, (size_t)NN * HID * sizeof(float), stream);
    hipMemsetAsync(cnt, 0, (size_t)NN * sizeof(float), stream);
    loop_accum<<<NE / 8, B, 0, stream>>>(dst, ea, la, cnt);
    loop_norm<<<(NN * HID + 255) / 256, B, 0, stream>>>(la, cnt);

    for (int l = 0; l < NLAYERS; ++l) {
        mgemm<0><<<gN128, B, 0, stream>>>(h,  wp.e[iL[l]].hi, wp.e[iL[l]].lo, lin_l_b + (size_t)l * HID, xl, NN, HID);
        mgemm<0><<<gN128, B, 0, stream>>>(h,  wp.e[iR[l]].hi, wp.e[iR[l]].lo, lin_r_b + (size_t)l * HID, xr, NN, HID);
        mgemm<0><<<gE128, B, 0, stream>>>(ea, wp.e[iE[l]].hi, wp.e[iE[l]].lo, nullptr, eeE, NE, HID);
        mgemm<0><<<gN128, B, 0, stream>>>(la, wp.e[iE[l]].hi, wp.e[iE[l]].lo, nullptr, eeL, NN, HID);

        hipMemsetAsync(segmax, 0, (size_t)NN * HEADS * sizeof(unsigned), stream);
        hipMemsetAsync(segsum, 0, (size_t)NN * HEADS * sizeof(float), stream);
        hipMemsetAsync(outb,   0, (size_t)NN * HID * sizeof(float), stream);

        att_logits <<<gEN, B, 0, stream>>>(src, dst, xl, xr, eeE, eeL,
                                           att + (size_t)l * HEADS * 32, logits, segmax);
        att_expsum <<<((NE + NN) * HEADS + 255) / 256, B, 0, stream>>>(dst, logits, segmax, segsum);
        att_scatter<<<gEN, B, 0, stream>>>(src, dst, xl, logits, segsum, outb);
        layer_epi  <<<(NN * HID + 255) / 256, B, 0, stream>>>(h, outb, conv_bias + (size_t)l * HID);
    }

    float* node_out = (float*)d_out;
    float* edge_out = (float*)d_out + (size_t)NN * NNC;

    // node classifier: hidden (gelu) via MFMA GEMM into eeL (dead), then reduce
    float* hidN = eeL;
    mgemm<1><<<gN128, B, 0, stream>>>(h, wp.e[iNC].hi, wp.e[iNC].lo, nc_b1, hidN, NN, HID);
    node_head<<<NN / 4, B, 0, stream>>>(hidN, nc_w2, nc_b2, node_out);

    // edge classifier decomposed: Pa = h@W1a, Pb = h@W1b, Pc = ea@W1c
    float* Pa = xl;   // dead after layers
    float* Pb = xr;
    float* Pc = eeE;
    mgemm<0><<<gN128, B, 0, stream>>>(h,  wp.e[iEA].hi, wp.e[iEA].lo, nullptr, Pa, NN, HID);
    mgemm<0><<<gN128, B, 0, stream>>>(h,  wp.e[iEB].hi, wp.e[iEB].lo, nullptr, Pb, NN, HID);
    mgemm<0><<<gE128, B, 0, stream>>>(ea, wp.e[iEC].hi, wp.e[iEC].lo, nullptr, Pc, NE, HID);
    edge_head<<<NE / 4, B, 0, stream>>>(src, dst, Pa, Pb, Pc, ec_b1, ec_w2, ec_b2, edge_out);
}